// Round 6
// baseline (54.543 us; speedup 1.0000x reference)
//
#include <hip/hip_runtime.h>
#include <stdint.h>

// Problem constants (from reference)
#define NB 16
#define NP 16384
#define NC 76
#define KSEL 1024
#define KOUT 256

#define CAND_MAX 6144
#define RANK_MAX 256

// ws layout (bytes)
#define WS_PROPS   0u         // 16*1024*8*4 = 524288
#define WS_BEV     524288u    // 16*1024*4*4 = 262144
#define WS_SELSC   786432u    // 16*1024*4   =  65536
#define WS_ROWNZ   851968u    // 16*16*8     =   2048
#define WS_KEYSEL  854016u    // 16*1024*8   = 131072

// ---------------------------------------------------------------------------
// Kernel 1: per-batch top-1024 radix select, adaptive. 8-bit digits, per-wave
// histograms (padded stride 257 to spread hot bins across banks). After each
// pass the boundary-bin survivors are compacted to an LDS buffer; once <=256
// remain, a direct count-rank finds the exact 1024th-largest key. Expected:
// pass0 (all 16K keys) -> ~4.7K candidates -> pass1 (~4.7K) -> ~18 -> rank.
// Fallback paths keep full correctness for any distribution.
// One block (1024 thr) per batch; writes 1024 winner keys (unordered).
// ---------------------------------------------------------------------------
__global__ __launch_bounds__(1024, 1) void k_select(
    const float* __restrict__ scores,       // [B][N]
    uint64_t* __restrict__ keysel)          // [B][1024]
{
    const int b = blockIdx.x, t = threadIdx.x;
    const int lane = t & 63;
    const int wave = t >> 6;
    const float4* sb4 = (const float4*)(scores + (size_t)b * NP);

    // 16 keys/thread, fully-coalesced float4 loads.
    // key = (mangled_score << 14) | (16383 - idx): all distinct, ordering
    // identical to jnp.argsort(-scores) (ties -> smaller idx first).
    uint64_t key[16];
#pragma unroll
    for (int q = 0; q < 4; ++q) {
        float4 v = sb4[(q << 10) + t];
        const float vs[4] = {v.x, v.y, v.z, v.w};
#pragma unroll
        for (int e = 0; e < 4; ++e) {
            int i = (((q << 10) + t) << 2) + e;
            uint32_t u = __float_as_uint(vs[e]);
            u ^= (u & 0x80000000u) ? 0xFFFFFFFFu : 0x80000000u;
            key[(q << 2) + e] = ((uint64_t)u << 14) | (uint64_t)(16383 - i);
        }
    }

    __shared__ unsigned int hist[16][257];   // per-wave, padded vs bank pileup
    __shared__ unsigned int wtot4[4];
    __shared__ uint64_t sh_prefix;
    __shared__ uint64_t sh_T;
    __shared__ unsigned int sh_rem;
    __shared__ unsigned int sh_cnt;
    __shared__ unsigned int cplace;
    __shared__ unsigned int selcnt;
    __shared__ uint64_t bufA[CAND_MAX];
    __shared__ uint64_t bufB[CAND_MAX];

    if (t == 0) { sh_prefix = 0ull; sh_rem = KSEL; selcnt = 0u; }

    const int shifts[6] = {38, 30, 22, 14, 6, 0};
    uint64_t prefix = 0ull, T = 0ull;
    unsigned rem = KSEL;
    int mode = 0;              // 0 = keys in regs; 1 = cur buf A; 2 = cur buf B
    unsigned curcnt = 0;
    int done = 0;

    for (int pass = 0; pass < 6 && !done; ++pass) {
        const int shift = shifts[pass];
        const int width = (pass == 5) ? 6 : 8;
        const unsigned mask = (1u << width) - 1u;
        const int nbins = 1 << width;

        for (int q = t; q < 16 * 257; q += 1024) ((unsigned*)hist)[q] = 0u;
        if (t == 0) cplace = 0u;
        __syncthreads();

        if (mode == 0) {
#pragma unroll
            for (int k = 0; k < 16; ++k) {
                uint64_t kk = key[k];
                if ((kk >> (shift + width)) == (prefix >> (shift + width)))
                    atomicAdd(&hist[wave][(unsigned)((kk >> shift) & mask)], 1u);
            }
        } else {
            const uint64_t* cur = (mode == 1) ? bufA : bufB;   // all match prefix
            for (unsigned i = t; i < curcnt; i += 1024)
                atomicAdd(&hist[wave][(unsigned)((cur[i] >> shift) & mask)], 1u);
        }
        __syncthreads();

        // parallel suffix scan over nbins (1 bin/thread)
        unsigned c_t = 0, v = 0;
        if (t < nbins) {
            unsigned s = 0;
#pragma unroll
            for (int w2 = 0; w2 < 16; ++w2) s += hist[w2][t];
            c_t = s;
            v = s;
#pragma unroll
            for (int o = 1; o < 64; o <<= 1) {
                unsigned u2 = __shfl_down(v, o);
                v += (lane + o < 64) ? u2 : 0u;
            }
            if (lane == 0) wtot4[wave] = v;
        }
        __syncthreads();
        if (t < nbins) {
            const int scanw = nbins >> 6;
            unsigned add = 0;
#pragma unroll
            for (int q = 0; q < 4; ++q) if (q > wave && q < scanw) add += wtot4[q];
            const unsigned S_t = v + add;        // suffix incl. bin t
            const unsigned S_n = S_t - c_t;      // suffix from bin t+1
            if (S_t >= rem && S_n < rem) {       // unique boundary bin
                sh_prefix = prefix | ((uint64_t)(unsigned)t << shift);
                sh_rem = rem - S_n;
                sh_cnt = c_t;
            }
        }
        __syncthreads();
        prefix = sh_prefix;
        rem = sh_rem;
        const unsigned cnt = sh_cnt;

        if (cnt == rem || pass == 5) {
            // all boundary-prefix keys are winners (low bits of prefix are 0)
            T = prefix; done = 1;
        } else {
            const bool to_rank = (cnt <= RANK_MAX);
            const bool to_comp = !to_rank && (cnt <= CAND_MAX);
            if (to_rank || to_comp) {
                uint64_t* dst = (mode == 1) ? bufB : bufA;
                if (mode == 0) {
#pragma unroll
                    for (int k = 0; k < 16; ++k) {
                        const uint64_t kk = key[k];
                        const bool p = (kk >> shift) == (prefix >> shift);
                        unsigned long long m = __ballot(p);
                        if (m) {
                            unsigned base;
                            if (lane == 0) base = atomicAdd(&cplace, (unsigned)__popcll(m));
                            base = __shfl(base, 0);
                            if (p) dst[base + (unsigned)__popcll(m & ((1ull << lane) - 1ull))] = kk;
                        }
                    }
                } else {
                    const uint64_t* cur = (mode == 1) ? bufA : bufB;
                    const unsigned cround = (curcnt + 1023u) & ~1023u;  // uniform trip
                    for (unsigned i = t; i < cround; i += 1024) {
                        const uint64_t kk = (i < curcnt) ? cur[i] : 0ull;
                        const bool p = (i < curcnt) && ((kk >> shift) == (prefix >> shift));
                        unsigned long long m = __ballot(p);
                        if (m) {
                            unsigned base;
                            if (lane == 0) base = atomicAdd(&cplace, (unsigned)__popcll(m));
                            base = __shfl(base, 0);
                            if (p) dst[base + (unsigned)__popcll(m & ((1ull << lane) - 1ull))] = kk;
                        }
                    }
                }
                __syncthreads();
                if (to_rank) {
                    // exact rank among <=256 candidates: T = rem-th largest
                    if (t < (int)cnt) {
                        const uint64_t me = dst[t];
                        unsigned r = 0;
                        for (unsigned j = 0; j < cnt; ++j) r += (dst[j] > me) ? 1u : 0u;
                        if (r == rem - 1u) sh_T = me;
                    }
                    __syncthreads();
                    T = sh_T; done = 1;
                } else {
                    mode = (mode == 1) ? 2 : 1;
                    curcnt = cnt;
                }
            }
            // else: cnt > CAND_MAX (only possible from REG mode) — next pass
            // stays predicated over registers.
        }
    }

    // winners: key >= T — exactly 1024 (keys distinct), order arbitrary
    uint64_t* kout = keysel + ((size_t)b << 10);
#pragma unroll
    for (int k = 0; k < 16; ++k) {
        const uint64_t kk = key[k];
        const bool p = kk >= T;
        unsigned long long m = __ballot(p);
        if (m) {
            unsigned base;
            if (lane == 0) base = atomicAdd(&selcnt, (unsigned)__popcll(m));
            base = __shfl(base, 0);
            if (p) kout[base + (unsigned)__popcll(m & ((1ull << lane) - 1ull))] = kk;
        }
    }
}

// ---------------------------------------------------------------------------
// Kernel 1b: rank-by-counting + decode + BEV. 16 blocks/batch x 64 thr
// (1 wave on every CU). Whole 304B reg row loaded as 19 float4 up front;
// the 1024-iter rank loop runs while those loads are in flight; residual
// selection via unrolled cndmask chains (no runtime-indexed arrays).
// ---------------------------------------------------------------------------
__global__ __launch_bounds__(64) void k_decode(
    const float* __restrict__ scores,   // [B][N]
    const float* __restrict__ reg,      // [B][N][76]
    const float* __restrict__ xyz,      // [B][N][3]
    const float* __restrict__ msz,      // [3]
    const uint64_t* __restrict__ keysel,// [B][1024]
    float* __restrict__ props,          // [B][1024][8]
    float* __restrict__ bev,            // [B][1024][4]
    float* __restrict__ selsc)          // [B][1024]
{
    const int b = blockIdx.x >> 4;
    const int r = blockIdx.x & 15;      // chunk of 64 keys
    const int t = threadIdx.x;

    __shared__ uint64_t sk[1024];
    const uint64_t* kin = keysel + ((size_t)b << 10);
    {
        const ulonglong2* k2 = (const ulonglong2*)kin;
        ulonglong2* s2 = (ulonglong2*)sk;
        for (int q = t; q < 512; q += 64) s2[q] = k2[q];
    }
    __syncthreads();

    const uint64_t kk = sk[(r << 6) + t];
    const int idx = 16383 - (int)(kk & 16383ull);

    // issue ALL global loads up front (independent)
    const float sc = scores[(size_t)b * NP + idx];
    const float* rr = reg + ((size_t)b * NP + idx) * NC;
    const float* xr = xyz + ((size_t)b * NP + idx) * 3;
    const float4* rr4 = (const float4*)rr;   // rows 16B-aligned (76*4=304)
    float4 R[19];
#pragma unroll
    for (int q = 0; q < 19; ++q) R[q] = rr4[q];
    const float x0 = xr[0], x1 = xr[1], x2 = xr[2];
    const float a0 = msz[0], a1 = msz[1], a2 = msz[2];

    // rank while loads are in flight (LDS broadcast, conflict-free)
    int rank = 0;
#pragma unroll 16
    for (int j = 0; j < 1024; ++j) rank += (sk[j] > kk) ? 1 : 0;

    const float vx [12] = {R[0].x,R[0].y,R[0].z,R[0].w, R[1].x,R[1].y,R[1].z,R[1].w, R[2].x,R[2].y,R[2].z,R[2].w};
    const float vzb[12] = {R[3].x,R[3].y,R[3].z,R[3].w, R[4].x,R[4].y,R[4].z,R[4].w, R[5].x,R[5].y,R[5].z,R[5].w};
    const float vxr[12] = {R[6].x,R[6].y,R[6].z,R[6].w, R[7].x,R[7].y,R[7].z,R[7].w, R[8].x,R[8].y,R[8].z,R[8].w};
    const float vzr[12] = {R[9].x,R[9].y,R[9].z,R[9].w, R[10].x,R[10].y,R[10].z,R[10].w, R[11].x,R[11].y,R[11].z,R[11].w};
    const float vrb[12] = {R[12].y,R[12].z,R[12].w, R[13].x,R[13].y,R[13].z,R[13].w, R[14].x,R[14].y,R[14].z,R[14].w, R[15].x};
    const float vrr[12] = {R[15].y,R[15].z,R[15].w, R[16].x,R[16].y,R[16].z,R[16].w, R[17].x,R[17].y,R[17].z,R[17].w, R[18].x};

    int xbin = 0; float bx = vx[0];
#pragma unroll
    for (int j = 1; j < 12; ++j) if (vx[j] > bx) { bx = vx[j]; xbin = j; }
    int zbin = 0; float bz = vzb[0];
#pragma unroll
    for (int j = 1; j < 12; ++j) if (vzb[j] > bz) { bz = vzb[j]; zbin = j; }
    int rybin = 0; float br = vrb[0];
#pragma unroll
    for (int j = 1; j < 12; ++j) if (vrb[j] > br) { br = vrb[j]; rybin = j; }

    float xres = vxr[0];
#pragma unroll
    for (int j = 1; j < 12; ++j) xres = (xbin == j) ? vxr[j] : xres;
    float zres = vzr[0];
#pragma unroll
    for (int j = 1; j < 12; ++j) zres = (zbin == j) ? vzr[j] : zres;
    float ryres = vrr[0];
#pragma unroll
    for (int j = 1; j < 12; ++j) ryres = (rybin == j) ? vrr[j] : ryres;

    float posx = ((float)xbin * 0.5f + 0.25f - 3.0f) + xres * 0.5f;
    float posz = ((float)zbin * 0.5f + 0.25f - 3.0f) + zres * 0.5f;
    float posy = x1 + R[12].x;           // rr[48]

    const float apc   = 0.5235987755982988f;   // 2*pi/12
    const float apch  = 0.2617993877991494f;   // apc/2
    const float twopi = 6.283185307179586f;
    const float fpi   = 3.141592653589793f;
    float ry = (float)rybin * apc + ryres * apch;
    ry = fmodf(ry, twopi);
    if (ry < 0.f) ry += twopi;
    if (ry > fpi) ry -= twopi;

    const float h = R[18].y * a0 + a0;   // rr[73..75]
    const float w = R[18].z * a1 + a1;
    const float l = R[18].w * a2 + a2;
    posx += x0;
    posz += x2;
    posy += h * 0.5f;                    // props[:,1] += h/2

    const size_t o = ((size_t)b << 10) | (size_t)rank;
    float* pp = props + o * 8;
    pp[0] = posx; pp[1] = posy; pp[2] = posz; pp[3] = h; pp[4] = w; pp[5] = l; pp[6] = ry;
    const float hl = l * 0.5f, hw = w * 0.5f;
    float* bb = bev + o * 4;
    bb[0] = posx - hl; bb[1] = posz - hw; bb[2] = posx + hl; bb[3] = posz + hw;
    selsc[o] = sc;
}

// ---------------------------------------------------------------------------
// Kernel 2: mark rows that suppress anything (loose threshold -> superset,
// exact decision recomputed in kernel 3). One block per (batch, 64-row word).
// Divide-free IoU test WITH sign guard (areas can be negative; for D<=0 the
// reference iou = inter/D <= 0 never suppresses).
// ---------------------------------------------------------------------------
__global__ __launch_bounds__(512) void k_overlap_flags(
    const float* __restrict__ bev,
    unsigned long long* __restrict__ rowNZ)
{
    const int b  = blockIdx.x >> 4;
    const int ic = blockIdx.x & 15;      // i-word index (rows ic*64 .. ic*64+63)
    const int t = threadIdx.x;
    const int lane = t & 63;
    const int wv = t >> 6;               // 0..7 -> j window [wv*128, wv*128+128)

    __shared__ float4 sbev[1024];
    __shared__ float sarea[1024];
    __shared__ unsigned long long sword;
    if (t == 0) sword = 0ull;

    const float4* gb = (const float4*)(bev + (((size_t)b << 10) * 4));
    for (int i = t; i < 1024; i += 512) {
        float4 v = gb[i];
        sbev[i] = v;
        sarea[i] = (v.z - v.x) * (v.w - v.y);
    }
    __syncthreads();

    const int i = (ic << 6) + lane;
    const float4 bi = sbev[i];
    const float aie = sarea[i] + 1e-8f;  // ai + eps

    bool any = false;
    const int j0 = wv << 7;
    if (j0 + 127 > i) {                  // wave-uniform skip for windows below i-word
#pragma unroll 4
        for (int j = j0; j < j0 + 128; ++j) {
            float4 bj = sbev[j];
            float ltx = fmaxf(bi.x, bj.x), lty = fmaxf(bi.y, bj.y);
            float rbx = fminf(bi.z, bj.z), rby = fminf(bi.w, bj.w);
            float w0 = fmaxf(rbx - ltx, 0.f), h0 = fmaxf(rby - lty, 0.f);
            float inter = w0 * h0;
            float sum = aie + sarea[j];          // ai + aj + eps
            // iou > 0.8495  <=>  (sum - inter > 0) && inter*1.8495 > 0.8495*sum
            any |= (j > i) & (sum > inter) & (inter * 1.8495f > 0.8495f * sum);
        }
    }
    unsigned long long m = __ballot(any);
    if (lane == 0 && m) atomicOr(&sword, m);
    __syncthreads();
    if (t == 0) rowNZ[b * 16 + ic] = sword;   // sole owner of this word
}

// ---------------------------------------------------------------------------
// Kernel 3: greedy NMS propagation (word-blocked; exact 0.85 threshold,
// rows rebuilt on demand via ballots) + output scatter. 1 block per batch.
// ---------------------------------------------------------------------------
__global__ __launch_bounds__(256) void k_nms_out(
    const unsigned long long* __restrict__ rowNZ,
    const float* __restrict__ bev,
    const float* __restrict__ props,
    const float* __restrict__ selsc,
    float* __restrict__ out)
{
    const int b = blockIdx.x;
    const int t = threadIdx.x;
    __shared__ float4 sbev[1024];
    __shared__ float sarea[1024];
    __shared__ unsigned long long keepW[16];
    __shared__ int wbase[16];
    __shared__ int sh_n;

    const float4* gb = (const float4*)(bev + (((size_t)b << 10) * 4));
    for (int i = t; i < 1024; i += 256) {
        float4 v = gb[i];
        sbev[i] = v;
        sarea[i] = (v.z - v.x) * (v.w - v.y);
    }
    __syncthreads();

    if (t < 64) {           // wave 0 does the (mostly trivial) serial pass
        const int lane = t;
        unsigned long long remv = 0ull;
        unsigned long long summ = (lane < 16) ? rowNZ[b * 16 + lane] : 0ull;
        for (int w = 0; w < 16; ++w) {
            unsigned long long rw = __shfl(remv, w);
            unsigned long long nz = __shfl(summ, w);
            unsigned long long keepw = ~rw;
            unsigned long long cand = nz & keepw;
            while (cand) {
                int bidx = __ffsll((long long)cand) - 1;
                cand &= cand - 1ull;
                if ((keepw >> bidx) & 1ull) {
                    const int i = (w << 6) + bidx;
                    const float4 bi = sbev[i];
                    const float ai = sarea[i];
                    unsigned long long row = 0ull;
#pragma unroll
                    for (int c = 0; c < 16; ++c) {
                        int j = (c << 6) + lane;
                        bool sup = false;
                        if (j > i) {
                            float4 bj = sbev[j];
                            float ltx = fmaxf(bi.x, bj.x), lty = fmaxf(bi.y, bj.y);
                            float rbx = fminf(bi.z, bj.z), rby = fminf(bi.w, bj.w);
                            float w0 = fmaxf(rbx - ltx, 0.f), h0 = fmaxf(rby - lty, 0.f);
                            float inter = w0 * h0;
                            float iou = inter / (ai + sarea[j] - inter + 1e-8f);
                            sup = iou > 0.85f;
                        }
                        unsigned long long word = __ballot(sup);
                        if (lane == c) row = word;
                    }
                    remv |= row;
                    unsigned long long roww = __shfl(row, w);
                    keepw &= ~roww;
                    cand  &= ~roww;
                }
            }
            if (lane == 0) keepW[w] = keepw;
        }
    }
    __syncthreads();

    if (t < 16) wbase[t] = (int)__popcll(keepW[t]);
    __syncthreads();
    if (t == 0) {
        int acc = 0;
        for (int w = 0; w < 16; ++w) { int c = wbase[w]; wbase[w] = acc; acc += c; }
        sh_n = acc;
    }
    __syncthreads();

    const int nk = sh_n;
    const int n = nk < KOUT ? nk : KOUT;
    const float* pb = props + (((size_t)b << 10) * 8);
    const float* scb = selsc + ((size_t)b << 10);
    float* ob = out + (size_t)b * KOUT * 7;
    float* os = out + (size_t)NB * KOUT * 7 + (size_t)b * KOUT;

    for (int i = t; i < 1024; i += 256) {
        const int w = i >> 6, bit = i & 63;
        unsigned long long kw = keepW[w];
        if ((kw >> bit) & 1ull) {
            int r = wbase[w] + (int)__popcll(kw & ((1ull << bit) - 1ull));
            if (r < KOUT) {
#pragma unroll
                for (int c = 0; c < 7; ++c) ob[r * 7 + c] = pb[i * 8 + c];
                os[r] = scb[i];
            }
        }
    }
    // zero unfilled slots (harness poisons d_out)
    {
        int r = t;
        if (r < KOUT && r >= n) {
#pragma unroll
            for (int c = 0; c < 7; ++c) ob[r * 7 + c] = 0.f;
            os[r] = 0.f;
        }
    }
}

// ---------------------------------------------------------------------------
extern "C" void kernel_launch(void* const* d_in, const int* in_sizes, int n_in,
                              void* d_out, int out_size, void* d_ws, size_t ws_size,
                              hipStream_t stream) {
    const float* scores = (const float*)d_in[0];
    const float* reg    = (const float*)d_in[1];
    const float* xyz    = (const float*)d_in[2];
    const float* msz    = (const float*)d_in[3];
    float* out = (float*)d_out;

    char* ws = (char*)d_ws;
    float* props = (float*)(ws + WS_PROPS);
    float* bev   = (float*)(ws + WS_BEV);
    float* selsc = (float*)(ws + WS_SELSC);
    unsigned long long* rowNZ = (unsigned long long*)(ws + WS_ROWNZ);
    uint64_t* keysel = (uint64_t*)(ws + WS_KEYSEL);

    k_select<<<dim3(NB), dim3(1024), 0, stream>>>(scores, keysel);
    k_decode<<<dim3(NB * 16), dim3(64), 0, stream>>>(scores, reg, xyz, msz,
                                                     keysel, props, bev, selsc);
    k_overlap_flags<<<dim3(NB * 16), dim3(512), 0, stream>>>(bev, rowNZ);
    k_nms_out<<<dim3(NB), dim3(256), 0, stream>>>(rowNZ, bev, props, selsc, out);
}

// Round 7
// 47.867 us; speedup vs baseline: 1.1395x; 1.1395x over previous
//
#include <hip/hip_runtime.h>
#include <stdint.h>

// Problem constants (from reference)
#define NB 16
#define NP 16384
#define NC 76
#define KSEL 1024
#define KOUT 256

// ws layout (bytes)
#define WS_PROPS   0u         // 16*1024*8*4 = 524288
#define WS_BEV     524288u    // 16*1024*4*4 = 262144
#define WS_SELSC   786432u    // 16*1024*4   =  65536
#define WS_ROWNZ   851968u    // 16*16*8     =   2048
#define WS_KEYSEL  854016u    // 16*1024*8   = 131072

// ---------------------------------------------------------------------------
// Kernel 1: per-batch top-1024 selection. 4-pass radix select (12/12/12/10-bit
// digits) over composite key (mangled_score << 14) | (16383 - idx); writes the
// 1024 winner keys (unordered) to ws. One block (1024 thr) per batch.
// (Round-5 version — part of the fastest measured run.)
// ---------------------------------------------------------------------------
__global__ __launch_bounds__(1024, 1) void k_select(
    const float* __restrict__ scores,       // [B][N]
    uint64_t* __restrict__ keysel)          // [B][1024]
{
    const int b = blockIdx.x;
    const int t = threadIdx.x;
    const int lane = t & 63;
    const int wave = t >> 6;

    const float* sb = scores + (size_t)b * NP;
    const float4* sb4 = (const float4*)sb;

    // 16 keys/thread, contiguous 16-score chunk per thread (4x float4).
    uint64_t key[16];
#pragma unroll
    for (int q = 0; q < 4; ++q) {
        float4 v = sb4[(t << 2) + q];
        const float vs[4] = {v.x, v.y, v.z, v.w};
#pragma unroll
        for (int e = 0; e < 4; ++e) {
            int i = (t << 4) + (q << 2) + e;
            uint32_t u = __float_as_uint(vs[e]);
            u ^= (u & 0x80000000u) ? 0xFFFFFFFFu : 0x80000000u;
            key[(q << 2) + e] = ((uint64_t)u << 14) | (uint64_t)(16383 - i);
        }
    }

    __shared__ unsigned int hist[4096];
    __shared__ unsigned int wtot[16];
    __shared__ uint64_t sh_prefix;
    __shared__ unsigned int sh_remaining;
    __shared__ unsigned int selcnt;
    if (t == 0) { sh_prefix = 0ull; sh_remaining = KSEL; selcnt = 0u; }

    const int shifts[4] = {34, 22, 10, 0};
    const int dbits [4] = {12, 12, 12, 10};

    uint64_t prefix = 0ull;
    for (int pass = 0; pass < 4; ++pass) {
        const int shift = shifts[pass];
        const int nb    = dbits[pass];
        const unsigned dmask = (1u << nb) - 1u;
        // zero histogram (4 words/thread)
#pragma unroll
        for (int q = 0; q < 4; ++q) hist[(q << 10) + t] = 0u;
        __syncthreads();
#pragma unroll
        for (int k = 0; k < 16; ++k) {
            uint64_t kk = key[k];
            if ((kk >> (shift + nb)) == (prefix >> (shift + nb)))
                atomicAdd(&hist[(unsigned)(kk >> shift) & dmask], 1u);
        }
        __syncthreads();
        // suffix scan: thread t owns bins 4t..4t+3
        const unsigned c0 = hist[(t << 2) + 0];
        const unsigned c1 = hist[(t << 2) + 1];
        const unsigned c2 = hist[(t << 2) + 2];
        const unsigned c3 = hist[(t << 2) + 3];
        const unsigned s = c0 + c1 + c2 + c3;
        unsigned v = s;
#pragma unroll
        for (int o = 1; o < 64; o <<= 1) {
            unsigned u = __shfl_down(v, o);
            v += (lane + o < 64) ? u : 0u;
        }
        if (lane == 0) wtot[wave] = v;       // wave-inclusive suffix total
        __syncthreads();
        unsigned add = 0;
#pragma unroll
        for (int w = 0; w < 16; ++w) if (w > wave) add += wtot[w];
        const unsigned Wt   = v + add;       // suffix from thread t (inclusive)
        const unsigned base = Wt - s;        // suffix from bin 4t+4
        const unsigned S3 = base + c3;
        const unsigned S2 = S3 + c2;
        const unsigned S1 = S2 + c1;
        const unsigned S0 = S1 + c0;
        const unsigned rem = sh_remaining;   // everyone reads rem
        int dig = -1; unsigned nrem = 0;
        if      (S3 >= rem && base < rem) { dig = (t << 2) + 3; nrem = rem - base; }
        else if (S2 >= rem && S3  < rem)  { dig = (t << 2) + 2; nrem = rem - S3; }
        else if (S1 >= rem && S2  < rem)  { dig = (t << 2) + 1; nrem = rem - S2; }
        else if (S0 >= rem && S1  < rem)  { dig = (t << 2) + 0; nrem = rem - S1; }
        __syncthreads();                     // all rem reads done before write
        if (dig >= 0) {                      // unique boundary thread
            sh_prefix |= ((uint64_t)(unsigned)dig) << shift;
            sh_remaining = nrem;
        }
        __syncthreads();
        prefix = sh_prefix;
    }
    const uint64_t T = prefix;   // exact 1024th-largest key (all keys distinct)

    // compact the exactly-1024 winners straight to ws (wave-aggregated)
    uint64_t* kout = keysel + ((size_t)b << 10);
#pragma unroll
    for (int k = 0; k < 16; ++k) {
        bool p = key[k] >= T;
        unsigned long long m = __ballot(p);
        if (m) {
            unsigned int base2;
            if (lane == 0) base2 = atomicAdd(&selcnt, (unsigned)__popcll(m));
            base2 = __shfl(base2, 0);
            if (p) kout[base2 + (unsigned)__popcll(m & ((1ull << lane) - 1ull))] = key[k];
        }
    }
}

// ---------------------------------------------------------------------------
// Kernel 1b: rank-by-counting + decode + BEV. 8 blocks/batch x 128 thr.
// Whole 304B reg row loaded as 19 upfront float4 (one latency round); the
// 1024-iter rank loop runs while those loads are in flight; residual
// selection via unrolled cndmask chains (no runtime-indexed arrays).
// ---------------------------------------------------------------------------
__global__ __launch_bounds__(128) void k_decode(
    const float* __restrict__ scores,   // [B][N]
    const float* __restrict__ reg,      // [B][N][76]
    const float* __restrict__ xyz,      // [B][N][3]
    const float* __restrict__ msz,      // [3]
    const uint64_t* __restrict__ keysel,// [B][1024]
    float* __restrict__ props,          // [B][1024][8]
    float* __restrict__ bev,            // [B][1024][4]
    float* __restrict__ selsc)          // [B][1024]
{
    const int b = blockIdx.x >> 3;
    const int r = blockIdx.x & 7;       // chunk of 128 keys
    const int t = threadIdx.x;

    __shared__ uint64_t sk[1024];
    const uint64_t* kin = keysel + ((size_t)b << 10);
    {
        const ulonglong2* k2 = (const ulonglong2*)kin;
        ulonglong2* s2 = (ulonglong2*)sk;
        for (int q = t; q < 512; q += 128) s2[q] = k2[q];
    }
    __syncthreads();

    const uint64_t kk = sk[(r << 7) + t];
    const int idx = 16383 - (int)(kk & 16383ull);

    // issue ALL global loads up front (independent)
    const float sc = scores[(size_t)b * NP + idx];
    const float* rr = reg + ((size_t)b * NP + idx) * NC;
    const float* xr = xyz + ((size_t)b * NP + idx) * 3;
    const float4* rr4 = (const float4*)rr;   // rows 16B-aligned (76*4=304)
    float4 R[19];
#pragma unroll
    for (int q = 0; q < 19; ++q) R[q] = rr4[q];
    const float x0 = xr[0], x1 = xr[1], x2 = xr[2];
    const float a0 = msz[0], a1 = msz[1], a2 = msz[2];

    // rank while loads are in flight (LDS broadcast, conflict-free)
    int rank = 0;
#pragma unroll 16
    for (int j = 0; j < 1024; ++j) rank += (sk[j] > kk) ? 1 : 0;

    const float vx [12] = {R[0].x,R[0].y,R[0].z,R[0].w, R[1].x,R[1].y,R[1].z,R[1].w, R[2].x,R[2].y,R[2].z,R[2].w};
    const float vzb[12] = {R[3].x,R[3].y,R[3].z,R[3].w, R[4].x,R[4].y,R[4].z,R[4].w, R[5].x,R[5].y,R[5].z,R[5].w};
    const float vxr[12] = {R[6].x,R[6].y,R[6].z,R[6].w, R[7].x,R[7].y,R[7].z,R[7].w, R[8].x,R[8].y,R[8].z,R[8].w};
    const float vzr[12] = {R[9].x,R[9].y,R[9].z,R[9].w, R[10].x,R[10].y,R[10].z,R[10].w, R[11].x,R[11].y,R[11].z,R[11].w};
    const float vrb[12] = {R[12].y,R[12].z,R[12].w, R[13].x,R[13].y,R[13].z,R[13].w, R[14].x,R[14].y,R[14].z,R[14].w, R[15].x};
    const float vrr[12] = {R[15].y,R[15].z,R[15].w, R[16].x,R[16].y,R[16].z,R[16].w, R[17].x,R[17].y,R[17].z,R[17].w, R[18].x};

    int xbin = 0; float bx = vx[0];
#pragma unroll
    for (int j = 1; j < 12; ++j) if (vx[j] > bx) { bx = vx[j]; xbin = j; }
    int zbin = 0; float bz = vzb[0];
#pragma unroll
    for (int j = 1; j < 12; ++j) if (vzb[j] > bz) { bz = vzb[j]; zbin = j; }
    int rybin = 0; float br = vrb[0];
#pragma unroll
    for (int j = 1; j < 12; ++j) if (vrb[j] > br) { br = vrb[j]; rybin = j; }

    float xres = vxr[0];
#pragma unroll
    for (int j = 1; j < 12; ++j) xres = (xbin == j) ? vxr[j] : xres;
    float zres = vzr[0];
#pragma unroll
    for (int j = 1; j < 12; ++j) zres = (zbin == j) ? vzr[j] : zres;
    float ryres = vrr[0];
#pragma unroll
    for (int j = 1; j < 12; ++j) ryres = (rybin == j) ? vrr[j] : ryres;

    float posx = ((float)xbin * 0.5f + 0.25f - 3.0f) + xres * 0.5f;
    float posz = ((float)zbin * 0.5f + 0.25f - 3.0f) + zres * 0.5f;
    float posy = x1 + R[12].x;           // rr[48]

    const float apc   = 0.5235987755982988f;   // 2*pi/12
    const float apch  = 0.2617993877991494f;   // apc/2
    const float twopi = 6.283185307179586f;
    const float fpi   = 3.141592653589793f;
    float ry = (float)rybin * apc + ryres * apch;
    ry = fmodf(ry, twopi);
    if (ry < 0.f) ry += twopi;
    if (ry > fpi) ry -= twopi;

    const float h = R[18].y * a0 + a0;   // rr[73..75]
    const float w = R[18].z * a1 + a1;
    const float l = R[18].w * a2 + a2;
    posx += x0;
    posz += x2;
    posy += h * 0.5f;                    // props[:,1] += h/2

    const size_t o = ((size_t)b << 10) | (size_t)rank;
    float* pp = props + o * 8;
    pp[0] = posx; pp[1] = posy; pp[2] = posz; pp[3] = h; pp[4] = w; pp[5] = l; pp[6] = ry;
    const float hl = l * 0.5f, hw = w * 0.5f;
    float* bb = bev + o * 4;
    bb[0] = posx - hl; bb[1] = posz - hw; bb[2] = posx + hl; bb[3] = posz + hw;
    selsc[o] = sc;
}

// ---------------------------------------------------------------------------
// Kernel 2: mark rows that suppress anything (loose threshold -> superset,
// exact decision recomputed in kernel 3). One block per (batch, 64-row word).
// Divide-free IoU test WITH sign guard (areas can be negative; for D<=0 the
// reference iou = inter/D <= 0 never suppresses).
// ---------------------------------------------------------------------------
__global__ __launch_bounds__(512) void k_overlap_flags(
    const float* __restrict__ bev,
    unsigned long long* __restrict__ rowNZ)
{
    const int b  = blockIdx.x >> 4;
    const int ic = blockIdx.x & 15;      // i-word index (rows ic*64 .. ic*64+63)
    const int t = threadIdx.x;
    const int lane = t & 63;
    const int wv = t >> 6;               // 0..7 -> j window [wv*128, wv*128+128)

    __shared__ float4 sbev[1024];
    __shared__ float sarea[1024];
    __shared__ unsigned long long sword;
    if (t == 0) sword = 0ull;

    const float4* gb = (const float4*)(bev + (((size_t)b << 10) * 4));
    for (int i = t; i < 1024; i += 512) {
        float4 v = gb[i];
        sbev[i] = v;
        sarea[i] = (v.z - v.x) * (v.w - v.y);
    }
    __syncthreads();

    const int i = (ic << 6) + lane;
    const float4 bi = sbev[i];
    const float aie = sarea[i] + 1e-8f;  // ai + eps

    bool any = false;
    const int j0 = wv << 7;
    if (j0 + 127 > i) {                  // wave-uniform skip for windows below i-word
#pragma unroll 4
        for (int j = j0; j < j0 + 128; ++j) {
            float4 bj = sbev[j];
            float ltx = fmaxf(bi.x, bj.x), lty = fmaxf(bi.y, bj.y);
            float rbx = fminf(bi.z, bj.z), rby = fminf(bi.w, bj.w);
            float w0 = fmaxf(rbx - ltx, 0.f), h0 = fmaxf(rby - lty, 0.f);
            float inter = w0 * h0;
            float sum = aie + sarea[j];          // ai + aj + eps
            // iou > 0.8495  <=>  (sum - inter > 0) && inter*1.8495 > 0.8495*sum
            any |= (j > i) & (sum > inter) & (inter * 1.8495f > 0.8495f * sum);
        }
    }
    unsigned long long m = __ballot(any);
    if (lane == 0 && m) atomicOr(&sword, m);
    __syncthreads();
    if (t == 0) rowNZ[b * 16 + ic] = sword;   // sole owner of this word
}

// ---------------------------------------------------------------------------
// Kernel 3: greedy NMS propagation (word-blocked; exact 0.85 threshold,
// rows rebuilt on demand via ballots) + output scatter. 1 block per batch.
// ---------------------------------------------------------------------------
__global__ __launch_bounds__(256) void k_nms_out(
    const unsigned long long* __restrict__ rowNZ,
    const float* __restrict__ bev,
    const float* __restrict__ props,
    const float* __restrict__ selsc,
    float* __restrict__ out)
{
    const int b = blockIdx.x;
    const int t = threadIdx.x;
    __shared__ float4 sbev[1024];
    __shared__ float sarea[1024];
    __shared__ unsigned long long keepW[16];
    __shared__ int wbase[16];
    __shared__ int sh_n;

    const float4* gb = (const float4*)(bev + (((size_t)b << 10) * 4));
    for (int i = t; i < 1024; i += 256) {
        float4 v = gb[i];
        sbev[i] = v;
        sarea[i] = (v.z - v.x) * (v.w - v.y);
    }
    __syncthreads();

    if (t < 64) {           // wave 0 does the (mostly trivial) serial pass
        const int lane = t;
        unsigned long long remv = 0ull;
        unsigned long long summ = (lane < 16) ? rowNZ[b * 16 + lane] : 0ull;
        for (int w = 0; w < 16; ++w) {
            unsigned long long rw = __shfl(remv, w);
            unsigned long long nz = __shfl(summ, w);
            unsigned long long keepw = ~rw;
            unsigned long long cand = nz & keepw;
            while (cand) {
                int bidx = __ffsll((long long)cand) - 1;
                cand &= cand - 1ull;
                if ((keepw >> bidx) & 1ull) {
                    const int i = (w << 6) + bidx;
                    const float4 bi = sbev[i];
                    const float ai = sarea[i];
                    unsigned long long row = 0ull;
#pragma unroll
                    for (int c = 0; c < 16; ++c) {
                        int j = (c << 6) + lane;
                        bool sup = false;
                        if (j > i) {
                            float4 bj = sbev[j];
                            float ltx = fmaxf(bi.x, bj.x), lty = fmaxf(bi.y, bj.y);
                            float rbx = fminf(bi.z, bj.z), rby = fminf(bi.w, bj.w);
                            float w0 = fmaxf(rbx - ltx, 0.f), h0 = fmaxf(rby - lty, 0.f);
                            float inter = w0 * h0;
                            float iou = inter / (ai + sarea[j] - inter + 1e-8f);
                            sup = iou > 0.85f;
                        }
                        unsigned long long word = __ballot(sup);
                        if (lane == c) row = word;
                    }
                    remv |= row;
                    unsigned long long roww = __shfl(row, w);
                    keepw &= ~roww;
                    cand  &= ~roww;
                }
            }
            if (lane == 0) keepW[w] = keepw;
        }
    }
    __syncthreads();

    if (t < 16) wbase[t] = (int)__popcll(keepW[t]);
    __syncthreads();
    if (t == 0) {
        int acc = 0;
        for (int w = 0; w < 16; ++w) { int c = wbase[w]; wbase[w] = acc; acc += c; }
        sh_n = acc;
    }
    __syncthreads();

    const int nk = sh_n;
    const int n = nk < KOUT ? nk : KOUT;
    const float* pb = props + (((size_t)b << 10) * 8);
    const float* scb = selsc + ((size_t)b << 10);
    float* ob = out + (size_t)b * KOUT * 7;
    float* os = out + (size_t)NB * KOUT * 7 + (size_t)b * KOUT;

    for (int i = t; i < 1024; i += 256) {
        const int w = i >> 6, bit = i & 63;
        unsigned long long kw = keepW[w];
        if ((kw >> bit) & 1ull) {
            int r = wbase[w] + (int)__popcll(kw & ((1ull << bit) - 1ull));
            if (r < KOUT) {
#pragma unroll
                for (int c = 0; c < 7; ++c) ob[r * 7 + c] = pb[i * 8 + c];
                os[r] = scb[i];
            }
        }
    }
    // zero unfilled slots (harness poisons d_out)
    {
        int r = t;
        if (r < KOUT && r >= n) {
#pragma unroll
            for (int c = 0; c < 7; ++c) ob[r * 7 + c] = 0.f;
            os[r] = 0.f;
        }
    }
}

// ---------------------------------------------------------------------------
extern "C" void kernel_launch(void* const* d_in, const int* in_sizes, int n_in,
                              void* d_out, int out_size, void* d_ws, size_t ws_size,
                              hipStream_t stream) {
    const float* scores = (const float*)d_in[0];
    const float* reg    = (const float*)d_in[1];
    const float* xyz    = (const float*)d_in[2];
    const float* msz    = (const float*)d_in[3];
    float* out = (float*)d_out;

    char* ws = (char*)d_ws;
    float* props = (float*)(ws + WS_PROPS);
    float* bev   = (float*)(ws + WS_BEV);
    float* selsc = (float*)(ws + WS_SELSC);
    unsigned long long* rowNZ = (unsigned long long*)(ws + WS_ROWNZ);
    uint64_t* keysel = (uint64_t*)(ws + WS_KEYSEL);

    k_select<<<dim3(NB), dim3(1024), 0, stream>>>(scores, keysel);
    k_decode<<<dim3(NB * 8), dim3(128), 0, stream>>>(scores, reg, xyz, msz,
                                                     keysel, props, bev, selsc);
    k_overlap_flags<<<dim3(NB * 16), dim3(512), 0, stream>>>(bev, rowNZ);
    k_nms_out<<<dim3(NB), dim3(256), 0, stream>>>(rowNZ, bev, props, selsc, out);
}